// Round 1
// baseline (410.933 us; speedup 1.0000x reference)
//
#include <hip/hip_runtime.h>
#include <hip/hip_bf16.h>

// y = -0.1 * x, elementwise over 16*4096*1024 fp32 elements.
// Pure HBM-bound streaming kernel: float4 vector loads/stores, 256-thread blocks.

__global__ __launch_bounds__(256) void scale_f32x4_kernel(
        const float4* __restrict__ x, float4* __restrict__ y, int n4) {
    int i = blockIdx.x * blockDim.x + threadIdx.x;
    if (i < n4) {
        float4 v = x[i];
        v.x *= -0.1f;
        v.y *= -0.1f;
        v.z *= -0.1f;
        v.w *= -0.1f;
        y[i] = v;
    }
}

extern "C" void kernel_launch(void* const* d_in, const int* in_sizes, int n_in,
                              void* d_out, int out_size, void* d_ws, size_t ws_size,
                              hipStream_t stream) {
    const float* x = (const float*)d_in[0];
    float* y = (float*)d_out;
    int n = in_sizes[0];           // 67,108,864 — divisible by 4
    int n4 = n / 4;                // 16,777,216 float4 elements
    int block = 256;
    int grid = (n4 + block - 1) / block;  // 65,536 blocks
    scale_f32x4_kernel<<<grid, block, 0, stream>>>(
        (const float4*)x, (float4*)y, n4);
}